// Round 6
// baseline (426.261 us; speedup 1.0000x reference)
//
#include <hip/hip_runtime.h>
#include <math.h>

#define G  17
#define Cg 32
#define B  4
#define C  544
#define H  96
#define W  96
#define HW (H*W)
#define TILES (HW/256)   // 36
#define NBLK (B*G*TILES) // 2448 (divisible by 8)
#define BN_EPS 1e-5f

typedef float  f32x4  __attribute__((ext_vector_type(4)));
typedef short  short8 __attribute__((ext_vector_type(8)));

// B (weights) LDS layout: 32 o-rows of 288 bf16 (576B) padded to 592B.
#define B_STRIDE 592
#define B_BYTES  (Cg*B_STRIDE)    // 18944

// XCD-chunked swizzle (round-4 verified: FETCH 925->87 MB).
__device__ __forceinline__ int swizzle_blk(int blk) {
    return (blk & 7) * (NBLK / 8) + (blk >> 3);
}

// ---------------------------------------------------------------------------
// Kernel 1: grouped 3x3 offset conv -> per-pixel affine aff[B][G][6][H][W]
// ---------------------------------------------------------------------------
__global__ __launch_bounds__(256) void offset_conv_kernel(
    const float* __restrict__ x, const float* __restrict__ w_off,
    const float* __restrict__ b_off, float* __restrict__ aff)
{
    __shared__ float wl[Cg*9*6];           // layout [i][t][c]
    const int blk  = swizzle_blk(blockIdx.x);
    const int tile = blk % TILES;
    const int g    = (blk / TILES) % G;
    const int b    = blk / (TILES*G);

    for (int l = threadIdx.x; l < Cg*9*6; l += 256) {
        int c = l % 6; int t = (l/6) % 9; int i = l/54;
        wl[l] = w_off[(size_t)(g*6 + c)*(Cg*9) + i*9 + t];
    }
    __syncthreads();

    const int p = tile*256 + threadIdx.x;
    const int h = p / W, w = p % W;

    float acc[6];
    #pragma unroll
    for (int c = 0; c < 6; ++c) acc[c] = b_off[g*6 + c];

    const float* xg = x + ((size_t)b*C + g*Cg)*HW;
    for (int i = 0; i < Cg; ++i) {
        const float* xc = xg + (size_t)i*HW;
        #pragma unroll
        for (int t = 0; t < 9; ++t) {
            const int dy = t/3 - 1, dx = t%3 - 1;
            const int yy = h + dy, xx = w + dx;
            float v = (yy >= 0 && yy < H && xx >= 0 && xx < W) ? xc[yy*W + xx] : 0.0f;
            #pragma unroll
            for (int c = 0; c < 6; ++c)
                acc[c] = fmaf(v, wl[(i*9 + t)*6 + c], acc[c]);
        }
    }

    float* ap = aff + ((size_t)(b*G + g)*6)*HW + p;
    #pragma unroll
    for (int c = 0; c < 6; ++c) ap[(size_t)c*HW] = acc[c];
}

// ---------------------------------------------------------------------------
// Kernel T: NCHW -> per-group channels-last  xT[(b*G+g)*HW + p][Cg]  (fp32)
// ---------------------------------------------------------------------------
__global__ __launch_bounds__(256) void transpose_kernel(
    const float* __restrict__ x, float* __restrict__ xT)
{
    __shared__ float t[256*33];            // +1 pad: conflict-free both phases
    const int blk  = swizzle_blk(blockIdx.x);
    const int tile = blk % TILES;
    const int g    = (blk / TILES) % G;
    const int b    = blk / (TILES*G);

    const float* xg = x + ((size_t)b*C + g*Cg)*HW + tile*256;
    #pragma unroll
    for (int i = 0; i < Cg; ++i)
        t[threadIdx.x*33 + i] = xg[(size_t)i*HW + threadIdx.x];
    __syncthreads();

    float4* dst = (float4*)(xT + ((size_t)(b*G + g)*HW + (size_t)tile*256)*Cg);
    #pragma unroll
    for (int r = 0; r < 8; ++r) {
        const int idx = r*256 + threadIdx.x;
        const int p = idx >> 3, i4 = idx & 7;
        const float* s = &t[p*33 + i4*4];
        dst[idx] = make_float4(s[0], s[1], s[2], s[3]);
    }
}

// ---------------------------------------------------------------------------
// Kernel 2: register-direct bf16 MFMA deformable conv + BN + residual ReLU.
// Lane (r15 = lane&15, koff = lane>>4) samples, for m=0..3, channels
// [koff*8, koff*8+8) of pixel wv*64 + m*16 + r15 -- which IS the MFMA
// A-fragment (A row=lane&15, k=(lane>>4)*8+e; m89-verified). So A never
// touches LDS and the main loop has NO barriers: waves run independently,
// 32 outstanding gathers each hide L2 latency. Weights staged bf16 in LDS
// once (single barrier). D: col=lane&15 -> o=n*16+r15; row=(lane>>4)*4+reg
// -> pixel m*16+koff*4+reg (same epilogue as round 5, verified).
// ---------------------------------------------------------------------------
__global__ __launch_bounds__(256) void deform_mfma_kernel(
    const float* __restrict__ x, const float* __restrict__ xT,
    const float* __restrict__ w_def, const float* __restrict__ aff,
    const float* __restrict__ gamma, const float* __restrict__ beta,
    const float* __restrict__ rmean, const float* __restrict__ rvar,
    float* __restrict__ out)
{
    __shared__ char Bsm[B_BYTES];

    const int blk  = swizzle_blk(blockIdx.x);
    const int tile = blk % TILES;
    const int g    = (blk / TILES) % G;
    const int b    = blk / (TILES*G);
    const int tid  = threadIdx.x;
    const int lane = tid & 63;
    const int wv   = tid >> 6;
    const int r15  = lane & 15;
    const int koff = lane >> 4;

    // ---- stage group weights to LDS (bf16): Bsm[o][K=t*32+i] ----
    for (int l = tid; l < Cg*288; l += 256) {
        const int o = l / 288, K = l % 288;
        const int t = K >> 5, i = K & 31;
        const float wt = w_def[(size_t)(g*Cg + o)*(Cg*9) + i*9 + t];
        *(__bf16*)(Bsm + o*B_STRIDE + K*2) = (__bf16)wt;
    }
    __syncthreads();   // the only barrier

    // ---- per-lane: affine params + coords for its 4 pixels ----
    const float* afb = aff + ((size_t)(b*G + g)*6)*HW;
    float a0[4], a1[4], a2[4], a3[4], a4[4], a5[4];
    float hf[4], wf[4];
    #pragma unroll
    for (int m = 0; m < 4; ++m) {
        const int p = tile*256 + wv*64 + m*16 + r15;
        a0[m] = afb[0*(size_t)HW + p];
        a1[m] = afb[1*(size_t)HW + p];
        a2[m] = afb[2*(size_t)HW + p];
        a3[m] = afb[3*(size_t)HW + p];
        a4[m] = afb[4*(size_t)HW + p];
        a5[m] = afb[5*(size_t)HW + p];
        hf[m] = (float)(p / W);
        wf[m] = (float)(p % W);
    }

    const float* xgT = xT + (size_t)(b*G + g)*HW*Cg + koff*8;

    f32x4 acc[4][2];
    #pragma unroll
    for (int m = 0; m < 4; ++m)
        #pragma unroll
        for (int n = 0; n < 2; ++n)
            acc[m][n] = (f32x4){0.f, 0.f, 0.f, 0.f};

    #pragma unroll 1
    for (int t = 0; t < 9; ++t) {
        const float kyf = (float)(t/3 - 1);
        const float kxf = (float)(t%3 - 1);

        short8 af[4];
        #pragma unroll
        for (int m = 0; m < 4; ++m) {
            const float py = hf[m] + kyf + (a0[m]*kyf + a1[m]*kxf + a2[m]);
            const float px = wf[m] + kxf + (a3[m]*kyf + a4[m]*kxf + a5[m]);
            const float y0f = floorf(py), x0f = floorf(px);
            const float fy = py - y0f,   fx = px - x0f;
            const int y0 = (int)y0f, x0 = (int)x0f;
            const int y1 = y0 + 1,   x1 = x0 + 1;
            const bool vy0 = (y0 >= 0) && (y0 < H);
            const bool vy1 = (y1 >= 0) && (y1 < H);
            const bool vx0 = (x0 >= 0) && (x0 < W);
            const bool vx1 = (x1 >= 0) && (x1 < W);
            const float w00 = (vy0 && vx0) ? (1.0f - fy)*(1.0f - fx) : 0.0f;
            const float w01 = (vy0 && vx1) ? (1.0f - fy)*fx          : 0.0f;
            const float w10 = (vy1 && vx0) ? fy*(1.0f - fx)          : 0.0f;
            const float w11 = (vy1 && vx1) ? fy*fx                   : 0.0f;
            const int y0c = min(max(y0, 0), H-1), y1c = min(max(y1, 0), H-1);
            const int x0c = min(max(x0, 0), W-1), x1c = min(max(x1, 0), W-1);
            const float4* c00 = (const float4*)(xgT + (size_t)(y0c*W + x0c)*Cg);
            const float4* c01 = (const float4*)(xgT + (size_t)(y0c*W + x1c)*Cg);
            const float4* c10 = (const float4*)(xgT + (size_t)(y1c*W + x0c)*Cg);
            const float4* c11 = (const float4*)(xgT + (size_t)(y1c*W + x1c)*Cg);

            const float4 p00a = c00[0], p00b = c00[1];
            const float4 p01a = c01[0], p01b = c01[1];
            const float4 p10a = c10[0], p10b = c10[1];
            const float4 p11a = c11[0], p11b = c11[1];

            union { short8 s; __bf16 e[8]; } u;
            u.e[0] = (__bf16)(w00*p00a.x + w01*p01a.x + w10*p10a.x + w11*p11a.x);
            u.e[1] = (__bf16)(w00*p00a.y + w01*p01a.y + w10*p10a.y + w11*p11a.y);
            u.e[2] = (__bf16)(w00*p00a.z + w01*p01a.z + w10*p10a.z + w11*p11a.z);
            u.e[3] = (__bf16)(w00*p00a.w + w01*p01a.w + w10*p10a.w + w11*p11a.w);
            u.e[4] = (__bf16)(w00*p00b.x + w01*p01b.x + w10*p10b.x + w11*p11b.x);
            u.e[5] = (__bf16)(w00*p00b.y + w01*p01b.y + w10*p10b.y + w11*p11b.y);
            u.e[6] = (__bf16)(w00*p00b.z + w01*p01b.z + w10*p10b.z + w11*p11b.z);
            u.e[7] = (__bf16)(w00*p00b.w + w01*p01b.w + w10*p10b.w + w11*p11b.w);
            af[m] = u.s;
        }

        #pragma unroll
        for (int n = 0; n < 2; ++n) {
            const short8 bf = *(const short8*)(Bsm + (n*16 + r15)*B_STRIDE + t*64 + koff*16);
            #pragma unroll
            for (int m = 0; m < 4; ++m)
                acc[m][n] = __builtin_amdgcn_mfma_f32_16x16x32_bf16(af[m], bf, acc[m][n], 0, 0, 0);
        }
    }

    // ---- epilogue: BN + residual + ReLU, 16B-chunk stores ----
    #pragma unroll
    for (int m = 0; m < 4; ++m) {
        const int pxg = tile*256 + wv*64 + m*16 + koff*4;
        #pragma unroll
        for (int n = 0; n < 2; ++n) {
            const int o = n*16 + r15;
            const int c = g*Cg + o;
            const float inv   = rsqrtf(rvar[c] + BN_EPS);
            const float scale = inv * gamma[c];
            const float shift = beta[c] - rmean[c]*scale;
            const size_t base = ((size_t)b*C + c)*HW + pxg;
            const float4 res = *(const float4*)(x + base);
            float4 ov;
            ov.x = fmaxf(acc[m][n][0]*scale + shift + res.x, 0.0f);
            ov.y = fmaxf(acc[m][n][1]*scale + shift + res.y, 0.0f);
            ov.z = fmaxf(acc[m][n][2]*scale + shift + res.z, 0.0f);
            ov.w = fmaxf(acc[m][n][3]*scale + shift + res.w, 0.0f);
            *(float4*)(out + base) = ov;
        }
    }
}

// ---------------------------------------------------------------------------
// Fallback (NCHW f32 path) if ws is too small for the transposed copy.
// ---------------------------------------------------------------------------
__global__ __launch_bounds__(256) void deform_conv_kernel(
    const float* __restrict__ x, const float* __restrict__ w_def,
    const float* __restrict__ aff, const float* __restrict__ gamma,
    const float* __restrict__ beta, const float* __restrict__ rmean,
    const float* __restrict__ rvar, float* __restrict__ out)
{
    __shared__ float wl[9*Cg*Cg];
    const int blk  = swizzle_blk(blockIdx.x);
    const int tile = blk % TILES;
    const int g    = (blk / TILES) % G;
    const int b    = blk / (TILES*G);

    for (int l = threadIdx.x; l < 9*Cg*Cg; l += 256) {
        int o = l & 31; int i = (l >> 5) & 31; int k = l >> 10;
        wl[l] = w_def[(size_t)(g*Cg + o)*(Cg*9) + i*9 + k];
    }
    __syncthreads();

    const int p = tile*256 + threadIdx.x;
    const int h = p / W, w = p % W;

    const float* ap = aff + ((size_t)(b*G + g)*6)*HW + p;
    const float a0 = ap[0*(size_t)HW], a1 = ap[1*(size_t)HW], a2 = ap[2*(size_t)HW];
    const float a3 = ap[3*(size_t)HW], a4 = ap[4*(size_t)HW], a5 = ap[5*(size_t)HW];

    float acc[Cg];
    #pragma unroll
    for (int o = 0; o < Cg; ++o) acc[o] = 0.0f;

    const float* xg = x + ((size_t)b*C + g*Cg)*HW;

    #pragma unroll
    for (int k = 0; k < 9; ++k) {
        const float kyf = (float)(k/3 - 1);
        const float kxf = (float)(k%3 - 1);
        const float offy = a0*kyf + a1*kxf + a2;
        const float offx = a3*kyf + a4*kxf + a5;
        const float py = (float)h + kyf + offy;
        const float px = (float)w + kxf + offx;
        const float y0f = floorf(py), x0f = floorf(px);
        const float fy = py - y0f,   fx = px - x0f;
        const int y0 = (int)y0f, x0 = (int)x0f;
        const int y1 = y0 + 1,   x1 = x0 + 1;
        const bool vy0 = (y0 >= 0) && (y0 < H);
        const bool vy1 = (y1 >= 0) && (y1 < H);
        const bool vx0 = (x0 >= 0) && (x0 < W);
        const bool vx1 = (x1 >= 0) && (x1 < W);
        const float w00 = (vy0 && vx0) ? (1.0f - fy)*(1.0f - fx) : 0.0f;
        const float w01 = (vy0 && vx1) ? (1.0f - fy)*fx          : 0.0f;
        const float w10 = (vy1 && vx0) ? fy*(1.0f - fx)          : 0.0f;
        const float w11 = (vy1 && vx1) ? fy*fx                   : 0.0f;
        const int y0c = min(max(y0, 0), H-1), y1c = min(max(y1, 0), H-1);
        const int x0c = min(max(x0, 0), W-1), x1c = min(max(x1, 0), W-1);
        const int p00 = y0c*W + x0c, p01 = y0c*W + x1c;
        const int p10 = y1c*W + x0c, p11 = y1c*W + x1c;

        const float* wk = &wl[k*Cg*Cg];
        for (int i = 0; i < Cg; ++i) {
            const float* xc = xg + (size_t)i*HW;
            const float v = w00*xc[p00] + w01*xc[p01] + w10*xc[p10] + w11*xc[p11];
            #pragma unroll
            for (int o = 0; o < Cg; ++o)
                acc[o] = fmaf(v, wk[i*Cg + o], acc[o]);
        }
    }

    float* op = out + ((size_t)b*C + g*Cg)*HW + p;
    #pragma unroll
    for (int o = 0; o < Cg; ++o) {
        const int c = g*Cg + o;
        const float inv = rsqrtf(rvar[c] + BN_EPS);
        float val = (acc[o] - rmean[c]) * (inv * gamma[c]) + beta[c];
        val += xg[(size_t)o*HW + p];
        op[(size_t)o*HW] = fmaxf(val, 0.0f);
    }
}

// ---------------------------------------------------------------------------
extern "C" void kernel_launch(void* const* d_in, const int* in_sizes, int n_in,
                              void* d_out, int out_size, void* d_ws, size_t ws_size,
                              hipStream_t stream) {
    const float* x     = (const float*)d_in[0];
    const float* w_off = (const float*)d_in[1];
    const float* b_off = (const float*)d_in[2];
    const float* w_def = (const float*)d_in[3];
    const float* gamma = (const float*)d_in[4];
    const float* beta  = (const float*)d_in[5];
    const float* rmean = (const float*)d_in[6];
    const float* rvar  = (const float*)d_in[7];
    float* out = (float*)d_out;

    const size_t AFF_BYTES = (size_t)B*G*6*HW*sizeof(float);   // ~15.0 MB
    const size_t XT_BYTES  = (size_t)B*G*HW*Cg*sizeof(float);  // ~80.2 MB
    float* aff = (float*)d_ws;

    offset_conv_kernel<<<NBLK, 256, 0, stream>>>(x, w_off, b_off, aff);

    if (ws_size >= AFF_BYTES + XT_BYTES) {
        float* xT = (float*)((char*)d_ws + AFF_BYTES);
        transpose_kernel<<<NBLK, 256, 0, stream>>>(x, xT);
        deform_mfma_kernel<<<NBLK, 256, 0, stream>>>(x, xT, w_def, aff, gamma,
                                                     beta, rmean, rvar, out);
    } else {
        deform_conv_kernel<<<NBLK, 256, 0, stream>>>(x, w_def, aff, gamma, beta,
                                                     rmean, rvar, out);
    }
}

// Round 7
// 225.499 us; speedup vs baseline: 1.8903x; 1.8903x over previous
//
#include <hip/hip_runtime.h>
#include <math.h>

#define G  17
#define Cg 32
#define B  4
#define C  544
#define H  96
#define W  96
#define HW (H*W)
#define TILES (HW/256)   // 36
#define NBLK (B*G*TILES) // 2448 (divisible by 8)
#define BN_EPS 1e-5f

typedef float  f32x4  __attribute__((ext_vector_type(4)));
typedef short  short8 __attribute__((ext_vector_type(8)));

// B (weights) LDS layout: 32 o-rows of 288 bf16 (576B) padded to 592B.
#define B_STRIDE 592
#define B_BYTES  (Cg*B_STRIDE)    // 18944

__device__ __forceinline__ float bf2f(unsigned short u) {
    union { unsigned int i; float f; } c;
    c.i = ((unsigned int)u) << 16;
    return c.f;
}

// XCD-chunked swizzle (round-4 verified: FETCH 925->87 MB).
__device__ __forceinline__ int swizzle_blk(int blk) {
    return (blk & 7) * (NBLK / 8) + (blk >> 3);
}

// ---------------------------------------------------------------------------
// Kernel 1: grouped 3x3 offset conv -> per-pixel affine aff[B][G][6][H][W]
// ---------------------------------------------------------------------------
__global__ __launch_bounds__(256) void offset_conv_kernel(
    const float* __restrict__ x, const float* __restrict__ w_off,
    const float* __restrict__ b_off, float* __restrict__ aff)
{
    __shared__ float wl[Cg*9*6];           // layout [i][t][c]
    const int blk  = swizzle_blk(blockIdx.x);
    const int tile = blk % TILES;
    const int g    = (blk / TILES) % G;
    const int b    = blk / (TILES*G);

    for (int l = threadIdx.x; l < Cg*9*6; l += 256) {
        int c = l % 6; int t = (l/6) % 9; int i = l/54;
        wl[l] = w_off[(size_t)(g*6 + c)*(Cg*9) + i*9 + t];
    }
    __syncthreads();

    const int p = tile*256 + threadIdx.x;
    const int h = p / W, w = p % W;

    float acc[6];
    #pragma unroll
    for (int c = 0; c < 6; ++c) acc[c] = b_off[g*6 + c];

    const float* xg = x + ((size_t)b*C + g*Cg)*HW;
    for (int i = 0; i < Cg; ++i) {
        const float* xc = xg + (size_t)i*HW;
        #pragma unroll
        for (int t = 0; t < 9; ++t) {
            const int dy = t/3 - 1, dx = t%3 - 1;
            const int yy = h + dy, xx = w + dx;
            float v = (yy >= 0 && yy < H && xx >= 0 && xx < W) ? xc[yy*W + xx] : 0.0f;
            #pragma unroll
            for (int c = 0; c < 6; ++c)
                acc[c] = fmaf(v, wl[(i*9 + t)*6 + c], acc[c]);
        }
    }

    float* ap = aff + ((size_t)(b*G + g)*6)*HW + p;
    #pragma unroll
    for (int c = 0; c < 6; ++c) ap[(size_t)c*HW] = acc[c];
}

// ---------------------------------------------------------------------------
// Kernel T: NCHW f32 -> per-group channels-last BF16  xT[(b*G+g)*HW + p][Cg]
// bf16 halves gather bytes AND makes one 32-ch pixel row = one 64B line.
// ---------------------------------------------------------------------------
__global__ __launch_bounds__(256) void transpose_kernel(
    const float* __restrict__ x, unsigned short* __restrict__ xT)
{
    __shared__ float t[256*33];            // +1 pad: conflict-free both phases
    const int blk  = swizzle_blk(blockIdx.x);
    const int tile = blk % TILES;
    const int g    = (blk / TILES) % G;
    const int b    = blk / (TILES*G);

    const float* xg = x + ((size_t)b*C + g*Cg)*HW + tile*256;
    #pragma unroll
    for (int i = 0; i < Cg; ++i)
        t[threadIdx.x*33 + i] = xg[(size_t)i*HW + threadIdx.x];
    __syncthreads();

    short8* dst = (short8*)(xT + ((size_t)(b*G + g)*HW + (size_t)tile*256)*Cg);
    #pragma unroll
    for (int r = 0; r < 4; ++r) {
        const int idx = r*256 + threadIdx.x;    // chunk: pixel idx>>2, 8ch (idx&3)*8
        const float* s = &t[(idx >> 2)*33 + (idx & 3)*8];
        union { short8 s8; __bf16 e[8]; } o;
        #pragma unroll
        for (int j = 0; j < 8; ++j) o.e[j] = (__bf16)s[j];
        dst[idx] = o.s8;
    }
}

// ---------------------------------------------------------------------------
// Kernel 2: register-direct bf16 MFMA deformable conv + BN + residual ReLU.
// Lane (r15, koff) samples, for m=0..3, channels [koff*8,+8) of pixel
// wv*64+m*16+r15 == the MFMA A-fragment (m89-verified). xT is bf16 so each
// corner slice is ONE short8 load (16 gathers/lane/tap, was 32). Blend in
// f32 after unpack. Weights staged bf16 in LDS once (single barrier).
// ---------------------------------------------------------------------------
__global__ __launch_bounds__(256) void deform_mfma_kernel(
    const float* __restrict__ x, const unsigned short* __restrict__ xT,
    const float* __restrict__ w_def, const float* __restrict__ aff,
    const float* __restrict__ gamma, const float* __restrict__ beta,
    const float* __restrict__ rmean, const float* __restrict__ rvar,
    float* __restrict__ out)
{
    __shared__ char Bsm[B_BYTES];

    const int blk  = swizzle_blk(blockIdx.x);
    const int tile = blk % TILES;
    const int g    = (blk / TILES) % G;
    const int b    = blk / (TILES*G);
    const int tid  = threadIdx.x;
    const int lane = tid & 63;
    const int wv   = tid >> 6;
    const int r15  = lane & 15;
    const int koff = lane >> 4;

    // ---- stage group weights to LDS (bf16): Bsm[o][K=t*32+i] ----
    for (int l = tid; l < Cg*288; l += 256) {
        const int o = l / 288, K = l % 288;
        const int t = K >> 5, i = K & 31;
        const float wt = w_def[(size_t)(g*Cg + o)*(Cg*9) + i*9 + t];
        *(__bf16*)(Bsm + o*B_STRIDE + K*2) = (__bf16)wt;
    }
    __syncthreads();   // the only barrier

    // ---- per-lane: affine params + coords for its 4 pixels ----
    const float* afb = aff + ((size_t)(b*G + g)*6)*HW;
    float a0[4], a1[4], a2[4], a3[4], a4[4], a5[4];
    float hf[4], wf[4];
    #pragma unroll
    for (int m = 0; m < 4; ++m) {
        const int p = tile*256 + wv*64 + m*16 + r15;
        a0[m] = afb[0*(size_t)HW + p];
        a1[m] = afb[1*(size_t)HW + p];
        a2[m] = afb[2*(size_t)HW + p];
        a3[m] = afb[3*(size_t)HW + p];
        a4[m] = afb[4*(size_t)HW + p];
        a5[m] = afb[5*(size_t)HW + p];
        hf[m] = (float)(p / W);
        wf[m] = (float)(p % W);
    }

    const unsigned short* xgT = xT + (size_t)(b*G + g)*HW*Cg + koff*8;

    f32x4 acc[4][2];
    #pragma unroll
    for (int m = 0; m < 4; ++m)
        #pragma unroll
        for (int n = 0; n < 2; ++n)
            acc[m][n] = (f32x4){0.f, 0.f, 0.f, 0.f};

    #pragma unroll 1
    for (int t = 0; t < 9; ++t) {
        const float kyf = (float)(t/3 - 1);
        const float kxf = (float)(t%3 - 1);

        short8 af[4];
        #pragma unroll
        for (int m = 0; m < 4; ++m) {
            const float py = hf[m] + kyf + (a0[m]*kyf + a1[m]*kxf + a2[m]);
            const float px = wf[m] + kxf + (a3[m]*kyf + a4[m]*kxf + a5[m]);
            const float y0f = floorf(py), x0f = floorf(px);
            const float fy = py - y0f,   fx = px - x0f;
            const int y0 = (int)y0f, x0 = (int)x0f;
            const int y1 = y0 + 1,   x1 = x0 + 1;
            const bool vy0 = (y0 >= 0) && (y0 < H);
            const bool vy1 = (y1 >= 0) && (y1 < H);
            const bool vx0 = (x0 >= 0) && (x0 < W);
            const bool vx1 = (x1 >= 0) && (x1 < W);
            const float w00 = (vy0 && vx0) ? (1.0f - fy)*(1.0f - fx) : 0.0f;
            const float w01 = (vy0 && vx1) ? (1.0f - fy)*fx          : 0.0f;
            const float w10 = (vy1 && vx0) ? fy*(1.0f - fx)          : 0.0f;
            const float w11 = (vy1 && vx1) ? fy*fx                   : 0.0f;
            const int y0c = min(max(y0, 0), H-1), y1c = min(max(y1, 0), H-1);
            const int x0c = min(max(x0, 0), W-1), x1c = min(max(x1, 0), W-1);

            union { short8 s; unsigned short us[8]; } u00, u01, u10, u11;
            u00.s = *(const short8*)(xgT + (size_t)(y0c*W + x0c)*Cg);
            u01.s = *(const short8*)(xgT + (size_t)(y0c*W + x1c)*Cg);
            u10.s = *(const short8*)(xgT + (size_t)(y1c*W + x0c)*Cg);
            u11.s = *(const short8*)(xgT + (size_t)(y1c*W + x1c)*Cg);

            union { short8 s; __bf16 e[8]; } r;
            #pragma unroll
            for (int j = 0; j < 8; ++j) {
                const float v = w00*bf2f(u00.us[j]) + w01*bf2f(u01.us[j])
                              + w10*bf2f(u10.us[j]) + w11*bf2f(u11.us[j]);
                r.e[j] = (__bf16)v;
            }
            af[m] = r.s;
        }

        #pragma unroll
        for (int n = 0; n < 2; ++n) {
            const short8 bf = *(const short8*)(Bsm + (n*16 + r15)*B_STRIDE + t*64 + koff*16);
            #pragma unroll
            for (int m = 0; m < 4; ++m)
                acc[m][n] = __builtin_amdgcn_mfma_f32_16x16x32_bf16(af[m], bf, acc[m][n], 0, 0, 0);
        }
    }

    // ---- epilogue: BN + residual + ReLU, 16B-chunk stores ----
    #pragma unroll
    for (int m = 0; m < 4; ++m) {
        const int pxg = tile*256 + wv*64 + m*16 + koff*4;
        #pragma unroll
        for (int n = 0; n < 2; ++n) {
            const int o = n*16 + r15;
            const int c = g*Cg + o;
            const float inv   = rsqrtf(rvar[c] + BN_EPS);
            const float scale = inv * gamma[c];
            const float shift = beta[c] - rmean[c]*scale;
            const size_t base = ((size_t)b*C + c)*HW + pxg;
            const float4 res = *(const float4*)(x + base);
            float4 ov;
            ov.x = fmaxf(acc[m][n][0]*scale + shift + res.x, 0.0f);
            ov.y = fmaxf(acc[m][n][1]*scale + shift + res.y, 0.0f);
            ov.z = fmaxf(acc[m][n][2]*scale + shift + res.z, 0.0f);
            ov.w = fmaxf(acc[m][n][3]*scale + shift + res.w, 0.0f);
            *(float4*)(out + base) = ov;
        }
    }
}

// ---------------------------------------------------------------------------
// Fallback (NCHW f32 path) if ws is too small for the transposed copy.
// ---------------------------------------------------------------------------
__global__ __launch_bounds__(256) void deform_conv_kernel(
    const float* __restrict__ x, const float* __restrict__ w_def,
    const float* __restrict__ aff, const float* __restrict__ gamma,
    const float* __restrict__ beta, const float* __restrict__ rmean,
    const float* __restrict__ rvar, float* __restrict__ out)
{
    __shared__ float wl[9*Cg*Cg];
    const int blk  = swizzle_blk(blockIdx.x);
    const int tile = blk % TILES;
    const int g    = (blk / TILES) % G;
    const int b    = blk / (TILES*G);

    for (int l = threadIdx.x; l < 9*Cg*Cg; l += 256) {
        int o = l & 31; int i = (l >> 5) & 31; int k = l >> 10;
        wl[l] = w_def[(size_t)(g*Cg + o)*(Cg*9) + i*9 + k];
    }
    __syncthreads();

    const int p = tile*256 + threadIdx.x;
    const int h = p / W, w = p % W;

    const float* ap = aff + ((size_t)(b*G + g)*6)*HW + p;
    const float a0 = ap[0*(size_t)HW], a1 = ap[1*(size_t)HW], a2 = ap[2*(size_t)HW];
    const float a3 = ap[3*(size_t)HW], a4 = ap[4*(size_t)HW], a5 = ap[5*(size_t)HW];

    float acc[Cg];
    #pragma unroll
    for (int o = 0; o < Cg; ++o) acc[o] = 0.0f;

    const float* xg = x + ((size_t)b*C + g*Cg)*HW;

    #pragma unroll
    for (int k = 0; k < 9; ++k) {
        const float kyf = (float)(k/3 - 1);
        const float kxf = (float)(k%3 - 1);
        const float offy = a0*kyf + a1*kxf + a2;
        const float offx = a3*kyf + a4*kxf + a5;
        const float py = (float)h + kyf + offy;
        const float px = (float)w + kxf + offx;
        const float y0f = floorf(py), x0f = floorf(px);
        const float fy = py - y0f,   fx = px - x0f;
        const int y0 = (int)y0f, x0 = (int)x0f;
        const int y1 = y0 + 1,   x1 = x0 + 1;
        const bool vy0 = (y0 >= 0) && (y0 < H);
        const bool vy1 = (y1 >= 0) && (y1 < H);
        const bool vx0 = (x0 >= 0) && (x0 < W);
        const bool vx1 = (x1 >= 0) && (x1 < W);
        const float w00 = (vy0 && vx0) ? (1.0f - fy)*(1.0f - fx) : 0.0f;
        const float w01 = (vy0 && vx1) ? (1.0f - fy)*fx          : 0.0f;
        const float w10 = (vy1 && vx0) ? fy*(1.0f - fx)          : 0.0f;
        const float w11 = (vy1 && vx1) ? fy*fx                   : 0.0f;
        const int y0c = min(max(y0, 0), H-1), y1c = min(max(y1, 0), H-1);
        const int x0c = min(max(x0, 0), W-1), x1c = min(max(x1, 0), W-1);
        const int p00 = y0c*W + x0c, p01 = y0c*W + x1c;
        const int p10 = y1c*W + x0c, p11 = y1c*W + x1c;

        const float* wk = &wl[k*Cg*Cg];
        for (int i = 0; i < Cg; ++i) {
            const float* xc = xg + (size_t)i*HW;
            const float v = w00*xc[p00] + w01*xc[p01] + w10*xc[p10] + w11*xc[p11];
            #pragma unroll
            for (int o = 0; o < Cg; ++o)
                acc[o] = fmaf(v, wk[i*Cg + o], acc[o]);
        }
    }

    float* op = out + ((size_t)b*C + g*Cg)*HW + p;
    #pragma unroll
    for (int o = 0; o < Cg; ++o) {
        const int c = g*Cg + o;
        const float inv = rsqrtf(rvar[c] + BN_EPS);
        float val = (acc[o] - rmean[c]) * (inv * gamma[c]) + beta[c];
        val += xg[(size_t)o*HW + p];
        op[(size_t)o*HW] = fmaxf(val, 0.0f);
    }
}

// ---------------------------------------------------------------------------
extern "C" void kernel_launch(void* const* d_in, const int* in_sizes, int n_in,
                              void* d_out, int out_size, void* d_ws, size_t ws_size,
                              hipStream_t stream) {
    const float* x     = (const float*)d_in[0];
    const float* w_off = (const float*)d_in[1];
    const float* b_off = (const float*)d_in[2];
    const float* w_def = (const float*)d_in[3];
    const float* gamma = (const float*)d_in[4];
    const float* beta  = (const float*)d_in[5];
    const float* rmean = (const float*)d_in[6];
    const float* rvar  = (const float*)d_in[7];
    float* out = (float*)d_out;

    const size_t AFF_BYTES = (size_t)B*G*6*HW*sizeof(float);           // ~15.0 MB
    const size_t XT_BYTES  = (size_t)B*G*HW*Cg*sizeof(unsigned short); // ~40.1 MB
    float* aff = (float*)d_ws;

    offset_conv_kernel<<<NBLK, 256, 0, stream>>>(x, w_off, b_off, aff);

    if (ws_size >= AFF_BYTES + XT_BYTES) {
        unsigned short* xT = (unsigned short*)((char*)d_ws + AFF_BYTES);
        transpose_kernel<<<NBLK, 256, 0, stream>>>(x, xT);
        deform_mfma_kernel<<<NBLK, 256, 0, stream>>>(x, xT, w_def, aff, gamma,
                                                     beta, rmean, rvar, out);
    } else {
        deform_conv_kernel<<<NBLK, 256, 0, stream>>>(x, w_def, aff, gamma, beta,
                                                     rmean, rvar, out);
    }
}

// Round 8
// 223.273 us; speedup vs baseline: 1.9091x; 1.0100x over previous
//
#include <hip/hip_runtime.h>
#include <math.h>

#define G  17
#define Cg 32
#define B  4
#define C  544
#define H  96
#define W  96
#define HW (H*W)
#define TILES (HW/256)   // 36
#define NBLK (B*G*TILES) // 2448 (divisible by 8)
#define BN_EPS 1e-5f

typedef float    f32x4  __attribute__((ext_vector_type(4)));
typedef short    short8 __attribute__((ext_vector_type(8)));
typedef _Float16 h2     __attribute__((ext_vector_type(2)));
typedef _Float16 h8     __attribute__((ext_vector_type(8)));

// B (weights) LDS layout: 32 o-rows of 288 fp16 (576B) padded to 592B.
#define B_STRIDE 592
#define B_BYTES  (Cg*B_STRIDE)    // 18944

// XCD-chunked swizzle (round-4 verified: FETCH 925->87 MB).
__device__ __forceinline__ int swizzle_blk(int blk) {
    return (blk & 7) * (NBLK / 8) + (blk >> 3);
}

// ---------------------------------------------------------------------------
// Kernel 1: grouped 3x3 offset conv -> per-pixel affine aff[B][G][6][H][W]
// ---------------------------------------------------------------------------
__global__ __launch_bounds__(256) void offset_conv_kernel(
    const float* __restrict__ x, const float* __restrict__ w_off,
    const float* __restrict__ b_off, float* __restrict__ aff)
{
    __shared__ float wl[Cg*9*6];           // layout [i][t][c]
    const int blk  = swizzle_blk(blockIdx.x);
    const int tile = blk % TILES;
    const int g    = (blk / TILES) % G;
    const int b    = blk / (TILES*G);

    for (int l = threadIdx.x; l < Cg*9*6; l += 256) {
        int c = l % 6; int t = (l/6) % 9; int i = l/54;
        wl[l] = w_off[(size_t)(g*6 + c)*(Cg*9) + i*9 + t];
    }
    __syncthreads();

    const int p = tile*256 + threadIdx.x;
    const int h = p / W, w = p % W;

    float acc[6];
    #pragma unroll
    for (int c = 0; c < 6; ++c) acc[c] = b_off[g*6 + c];

    const float* xg = x + ((size_t)b*C + g*Cg)*HW;
    for (int i = 0; i < Cg; ++i) {
        const float* xc = xg + (size_t)i*HW;
        #pragma unroll
        for (int t = 0; t < 9; ++t) {
            const int dy = t/3 - 1, dx = t%3 - 1;
            const int yy = h + dy, xx = w + dx;
            float v = (yy >= 0 && yy < H && xx >= 0 && xx < W) ? xc[yy*W + xx] : 0.0f;
            #pragma unroll
            for (int c = 0; c < 6; ++c)
                acc[c] = fmaf(v, wl[(i*9 + t)*6 + c], acc[c]);
        }
    }

    float* ap = aff + ((size_t)(b*G + g)*6)*HW + p;
    #pragma unroll
    for (int c = 0; c < 6; ++c) ap[(size_t)c*HW] = acc[c];
}

// ---------------------------------------------------------------------------
// Kernel T: NCHW f32 -> per-group channels-last FP16  xT[(b*G+g)*HW + p][Cg]
// fp16: 16B = one 8-channel corner slice; one 64B line = one 32-ch pixel row.
// ---------------------------------------------------------------------------
__global__ __launch_bounds__(256) void transpose_kernel(
    const float* __restrict__ x, _Float16* __restrict__ xT)
{
    __shared__ float t[256*33];            // +1 pad: conflict-free both phases
    const int blk  = swizzle_blk(blockIdx.x);
    const int tile = blk % TILES;
    const int g    = (blk / TILES) % G;
    const int b    = blk / (TILES*G);

    const float* xg = x + ((size_t)b*C + g*Cg)*HW + tile*256;
    #pragma unroll
    for (int i = 0; i < Cg; ++i)
        t[threadIdx.x*33 + i] = xg[(size_t)i*HW + threadIdx.x];
    __syncthreads();

    h8* dst = (h8*)(xT + ((size_t)(b*G + g)*HW + (size_t)tile*256)*Cg);
    #pragma unroll
    for (int r = 0; r < 4; ++r) {
        const int idx = r*256 + threadIdx.x;    // chunk: pixel idx>>2, 8ch (idx&3)*8
        const float* s = &t[(idx >> 2)*33 + (idx & 3)*8];
        h8 o;
        #pragma unroll
        for (int j = 0; j < 8; ++j) o[j] = (_Float16)s[j];
        dst[idx] = o;
    }
}

// ---------------------------------------------------------------------------
// Kernel 2: register-direct fp16 MFMA deformable conv + BN + residual ReLU.
// Lane (r15, koff) samples, for m=0..3, channels [koff*8,+8) of pixel
// wv*64+m*16+r15 == the MFMA A-fragment. Corner slice = ONE 16B load;
// bilinear blend in PACKED fp16 (v_pk_fma_f16, scalar-broadcast weights):
// 16 pk-ops per (m,tap) vs ~70 f32 ops in the bf16 version. Weights staged
// fp16 in LDS once (single barrier). mfma_f32_16x16x32_f16 (same geometry).
// ---------------------------------------------------------------------------
__global__ __launch_bounds__(256) void deform_mfma_kernel(
    const float* __restrict__ x, const _Float16* __restrict__ xT,
    const float* __restrict__ w_def, const float* __restrict__ aff,
    const float* __restrict__ gamma, const float* __restrict__ beta,
    const float* __restrict__ rmean, const float* __restrict__ rvar,
    float* __restrict__ out)
{
    __shared__ char Bsm[B_BYTES];

    const int blk  = swizzle_blk(blockIdx.x);
    const int tile = blk % TILES;
    const int g    = (blk / TILES) % G;
    const int b    = blk / (TILES*G);
    const int tid  = threadIdx.x;
    const int lane = tid & 63;
    const int wv   = tid >> 6;
    const int r15  = lane & 15;
    const int koff = lane >> 4;

    // ---- stage group weights to LDS (fp16): Bsm[o][K=t*32+i] ----
    for (int l = tid; l < Cg*288; l += 256) {
        const int o = l / 288, K = l % 288;
        const int t = K >> 5, i = K & 31;
        const float wt = w_def[(size_t)(g*Cg + o)*(Cg*9) + i*9 + t];
        *(_Float16*)(Bsm + o*B_STRIDE + K*2) = (_Float16)wt;
    }
    __syncthreads();   // the only barrier

    // ---- per-lane: affine params + coords for its 4 pixels ----
    const float* afb = aff + ((size_t)(b*G + g)*6)*HW;
    float a0[4], a1[4], a2[4], a3[4], a4[4], a5[4];
    float hf[4], wf[4];
    #pragma unroll
    for (int m = 0; m < 4; ++m) {
        const int p = tile*256 + wv*64 + m*16 + r15;
        a0[m] = afb[0*(size_t)HW + p];
        a1[m] = afb[1*(size_t)HW + p];
        a2[m] = afb[2*(size_t)HW + p];
        a3[m] = afb[3*(size_t)HW + p];
        a4[m] = afb[4*(size_t)HW + p];
        a5[m] = afb[5*(size_t)HW + p];
        hf[m] = (float)(p / W);
        wf[m] = (float)(p % W);
    }

    const _Float16* xgT = xT + (size_t)(b*G + g)*HW*Cg + koff*8;

    f32x4 acc[4][2];
    #pragma unroll
    for (int m = 0; m < 4; ++m)
        #pragma unroll
        for (int n = 0; n < 2; ++n)
            acc[m][n] = (f32x4){0.f, 0.f, 0.f, 0.f};

    #pragma unroll 1
    for (int t = 0; t < 9; ++t) {
        const float kyf = (float)(t/3 - 1);
        const float kxf = (float)(t%3 - 1);

        h8 af[4];
        #pragma unroll
        for (int m = 0; m < 4; ++m) {
            const float py = hf[m] + kyf + (a0[m]*kyf + a1[m]*kxf + a2[m]);
            const float px = wf[m] + kxf + (a3[m]*kyf + a4[m]*kxf + a5[m]);
            const float y0f = floorf(py), x0f = floorf(px);
            const float fy = py - y0f,   fx = px - x0f;
            const int y0 = (int)y0f, x0 = (int)x0f;
            const int y1 = y0 + 1,   x1 = x0 + 1;
            const bool vy0 = (y0 >= 0) && (y0 < H);
            const bool vy1 = (y1 >= 0) && (y1 < H);
            const bool vx0 = (x0 >= 0) && (x0 < W);
            const bool vx1 = (x1 >= 0) && (x1 < W);
            const float w00f = (vy0 && vx0) ? (1.0f - fy)*(1.0f - fx) : 0.0f;
            const float w01f = (vy0 && vx1) ? (1.0f - fy)*fx          : 0.0f;
            const float w10f = (vy1 && vx0) ? fy*(1.0f - fx)          : 0.0f;
            const float w11f = (vy1 && vx1) ? fy*fx                   : 0.0f;
            const int y0c = min(max(y0, 0), H-1), y1c = min(max(y1, 0), H-1);
            const int x0c = min(max(x0, 0), W-1), x1c = min(max(x1, 0), W-1);

            union { short8 s; h2 h[4]; h8 v; } u00, u01, u10, u11, r;
            u00.s = *(const short8*)(xgT + (size_t)(y0c*W + x0c)*Cg);
            u01.s = *(const short8*)(xgT + (size_t)(y0c*W + x1c)*Cg);
            u10.s = *(const short8*)(xgT + (size_t)(y1c*W + x0c)*Cg);
            u11.s = *(const short8*)(xgT + (size_t)(y1c*W + x1c)*Cg);

            const _Float16 W00 = (_Float16)w00f, W01 = (_Float16)w01f;
            const _Float16 W10 = (_Float16)w10f, W11 = (_Float16)w11f;
            #pragma unroll
            for (int j = 0; j < 4; ++j)
                r.h[j] = W00*u00.h[j] + W01*u01.h[j] + W10*u10.h[j] + W11*u11.h[j];
            af[m] = r.v;
        }

        #pragma unroll
        for (int n = 0; n < 2; ++n) {
            const h8 bf = *(const h8*)(Bsm + (n*16 + r15)*B_STRIDE + t*64 + koff*16);
            #pragma unroll
            for (int m = 0; m < 4; ++m)
                acc[m][n] = __builtin_amdgcn_mfma_f32_16x16x32_f16(af[m], bf, acc[m][n], 0, 0, 0);
        }
    }

    // ---- epilogue: BN + residual + ReLU, 16B-chunk stores ----
    #pragma unroll
    for (int m = 0; m < 4; ++m) {
        const int pxg = tile*256 + wv*64 + m*16 + koff*4;
        #pragma unroll
        for (int n = 0; n < 2; ++n) {
            const int o = n*16 + r15;
            const int c = g*Cg + o;
            const float inv   = rsqrtf(rvar[c] + BN_EPS);
            const float scale = inv * gamma[c];
            const float shift = beta[c] - rmean[c]*scale;
            const size_t base = ((size_t)b*C + c)*HW + pxg;
            const float4 res = *(const float4*)(x + base);
            float4 ov;
            ov.x = fmaxf(acc[m][n][0]*scale + shift + res.x, 0.0f);
            ov.y = fmaxf(acc[m][n][1]*scale + shift + res.y, 0.0f);
            ov.z = fmaxf(acc[m][n][2]*scale + shift + res.z, 0.0f);
            ov.w = fmaxf(acc[m][n][3]*scale + shift + res.w, 0.0f);
            *(float4*)(out + base) = ov;
        }
    }
}

// ---------------------------------------------------------------------------
// Fallback (NCHW f32 path) if ws is too small for the transposed copy.
// ---------------------------------------------------------------------------
__global__ __launch_bounds__(256) void deform_conv_kernel(
    const float* __restrict__ x, const float* __restrict__ w_def,
    const float* __restrict__ aff, const float* __restrict__ gamma,
    const float* __restrict__ beta, const float* __restrict__ rmean,
    const float* __restrict__ rvar, float* __restrict__ out)
{
    __shared__ float wl[9*Cg*Cg];
    const int blk  = swizzle_blk(blockIdx.x);
    const int tile = blk % TILES;
    const int g    = (blk / TILES) % G;
    const int b    = blk / (TILES*G);

    for (int l = threadIdx.x; l < 9*Cg*Cg; l += 256) {
        int o = l & 31; int i = (l >> 5) & 31; int k = l >> 10;
        wl[l] = w_def[(size_t)(g*Cg + o)*(Cg*9) + i*9 + k];
    }
    __syncthreads();

    const int p = tile*256 + threadIdx.x;
    const int h = p / W, w = p % W;

    const float* ap = aff + ((size_t)(b*G + g)*6)*HW + p;
    const float a0 = ap[0*(size_t)HW], a1 = ap[1*(size_t)HW], a2 = ap[2*(size_t)HW];
    const float a3 = ap[3*(size_t)HW], a4 = ap[4*(size_t)HW], a5 = ap[5*(size_t)HW];

    float acc[Cg];
    #pragma unroll
    for (int o = 0; o < Cg; ++o) acc[o] = 0.0f;

    const float* xg = x + ((size_t)b*C + g*Cg)*HW;

    #pragma unroll
    for (int k = 0; k < 9; ++k) {
        const float kyf = (float)(k/3 - 1);
        const float kxf = (float)(k%3 - 1);
        const float offy = a0*kyf + a1*kxf + a2;
        const float offx = a3*kyf + a4*kxf + a5;
        const float py = (float)h + kyf + offy;
        const float px = (float)w + kxf + offx;
        const float y0f = floorf(py), x0f = floorf(px);
        const float fy = py - y0f,   fx = px - x0f;
        const int y0 = (int)y0f, x0 = (int)x0f;
        const int y1 = y0 + 1,   x1 = x0 + 1;
        const bool vy0 = (y0 >= 0) && (y0 < H);
        const bool vy1 = (y1 >= 0) && (y1 < H);
        const bool vx0 = (x0 >= 0) && (x0 < W);
        const bool vx1 = (x1 >= 0) && (x1 < W);
        const float w00 = (vy0 && vx0) ? (1.0f - fy)*(1.0f - fx) : 0.0f;
        const float w01 = (vy0 && vx1) ? (1.0f - fy)*fx          : 0.0f;
        const float w10 = (vy1 && vx0) ? fy*(1.0f - fx)          : 0.0f;
        const float w11 = (vy1 && vx1) ? fy*fx                   : 0.0f;
        const int y0c = min(max(y0, 0), H-1), y1c = min(max(y1, 0), H-1);
        const int x0c = min(max(x0, 0), W-1), x1c = min(max(x1, 0), W-1);
        const int p00 = y0c*W + x0c, p01 = y0c*W + x1c;
        const int p10 = y1c*W + x0c, p11 = y1c*W + x1c;

        const float* wk = &wl[k*Cg*Cg];
        for (int i = 0; i < Cg; ++i) {
            const float* xc = xg + (size_t)i*HW;
            const float v = w00*xc[p00] + w01*xc[p01] + w10*xc[p10] + w11*xc[p11];
            #pragma unroll
            for (int o = 0; o < Cg; ++o)
                acc[o] = fmaf(v, wk[i*Cg + o], acc[o]);
        }
    }

    float* op = out + ((size_t)b*C + g*Cg)*HW + p;
    #pragma unroll
    for (int o = 0; o < Cg; ++o) {
        const int c = g*Cg + o;
        const float inv = rsqrtf(rvar[c] + BN_EPS);
        float val = (acc[o] - rmean[c]) * (inv * gamma[c]) + beta[c];
        val += xg[(size_t)o*HW + p];
        op[(size_t)o*HW] = fmaxf(val, 0.0f);
    }
}

// ---------------------------------------------------------------------------
extern "C" void kernel_launch(void* const* d_in, const int* in_sizes, int n_in,
                              void* d_out, int out_size, void* d_ws, size_t ws_size,
                              hipStream_t stream) {
    const float* x     = (const float*)d_in[0];
    const float* w_off = (const float*)d_in[1];
    const float* b_off = (const float*)d_in[2];
    const float* w_def = (const float*)d_in[3];
    const float* gamma = (const float*)d_in[4];
    const float* beta  = (const float*)d_in[5];
    const float* rmean = (const float*)d_in[6];
    const float* rvar  = (const float*)d_in[7];
    float* out = (float*)d_out;

    const size_t AFF_BYTES = (size_t)B*G*6*HW*sizeof(float);       // ~15.0 MB
    const size_t XT_BYTES  = (size_t)B*G*HW*Cg*sizeof(_Float16);   // ~40.1 MB
    float* aff = (float*)d_ws;

    offset_conv_kernel<<<NBLK, 256, 0, stream>>>(x, w_off, b_off, aff);

    if (ws_size >= AFF_BYTES + XT_BYTES) {
        _Float16* xT = (_Float16*)((char*)d_ws + AFF_BYTES);
        transpose_kernel<<<NBLK, 256, 0, stream>>>(x, xT);
        deform_mfma_kernel<<<NBLK, 256, 0, stream>>>(x, xT, w_def, aff, gamma,
                                                     beta, rmean, rvar, out);
    } else {
        deform_conv_kernel<<<NBLK, 256, 0, stream>>>(x, w_def, aff, gamma, beta,
                                                     rmean, rvar, out);
    }
}

// Round 9
// 189.712 us; speedup vs baseline: 2.2469x; 1.1769x over previous
//
#include <hip/hip_runtime.h>
#include <math.h>

#define G  17
#define Cg 32
#define B  4
#define C  544
#define H  96
#define W  96
#define HW (H*W)
#define TILES 36         // 6x6 tiles of 16x16 pixels
#define NBLK (B*G*TILES) // 2448 (divisible by 8)
#define BN_EPS 1e-5f

typedef float    f32x4  __attribute__((ext_vector_type(4)));
typedef short    short8 __attribute__((ext_vector_type(8)));
typedef _Float16 h2     __attribute__((ext_vector_type(2)));
typedef _Float16 h8     __attribute__((ext_vector_type(8)));

// ---- deform LDS layout ----
// Window: 24x24 positions (16x16 tile + halo 4), 32ch fp16 per position,
// row stride 80B (64B data + 16B pad): 16B-aligned, pos*20 dwords %32 gives
// 8 distinct bank starts -> ~2-way conflicts (free, m136).
#define WIN       24
#define WPOS      (WIN*WIN)       // 576
#define W_STRIDE  80
#define W_BYTES   (WPOS*W_STRIDE) // 46080
// Weights: 32 o-rows of 288 fp16 (576B) padded to 592B.
#define B_STRIDE  592
#define B_BYTES   (Cg*B_STRIDE)   // 18944
#define SMEM_BYTES (W_BYTES + B_BYTES) // 65024 (<64KiB static limit)

// XCD-chunked swizzle (round-4 verified: FETCH 925->87 MB).
__device__ __forceinline__ int swizzle_blk(int blk) {
    return (blk & 7) * (NBLK / 8) + (blk >> 3);
}

// ---------------------------------------------------------------------------
// Kernel 1: grouped 3x3 offset conv -> per-pixel affine aff[B][G][6][H][W]
// (linear 256-pixel strips; unchanged from round 4)
// ---------------------------------------------------------------------------
__global__ __launch_bounds__(256) void offset_conv_kernel(
    const float* __restrict__ x, const float* __restrict__ w_off,
    const float* __restrict__ b_off, float* __restrict__ aff)
{
    __shared__ float wl[Cg*9*6];           // layout [i][t][c]
    const int blk  = swizzle_blk(blockIdx.x);
    const int tile = blk % TILES;
    const int g    = (blk / TILES) % G;
    const int b    = blk / (TILES*G);

    for (int l = threadIdx.x; l < Cg*9*6; l += 256) {
        int c = l % 6; int t = (l/6) % 9; int i = l/54;
        wl[l] = w_off[(size_t)(g*6 + c)*(Cg*9) + i*9 + t];
    }
    __syncthreads();

    const int p = tile*256 + threadIdx.x;
    const int h = p / W, w = p % W;

    float acc[6];
    #pragma unroll
    for (int c = 0; c < 6; ++c) acc[c] = b_off[g*6 + c];

    const float* xg = x + ((size_t)b*C + g*Cg)*HW;
    for (int i = 0; i < Cg; ++i) {
        const float* xc = xg + (size_t)i*HW;
        #pragma unroll
        for (int t = 0; t < 9; ++t) {
            const int dy = t/3 - 1, dx = t%3 - 1;
            const int yy = h + dy, xx = w + dx;
            float v = (yy >= 0 && yy < H && xx >= 0 && xx < W) ? xc[yy*W + xx] : 0.0f;
            #pragma unroll
            for (int c = 0; c < 6; ++c)
                acc[c] = fmaf(v, wl[(i*9 + t)*6 + c], acc[c]);
        }
    }

    float* ap = aff + ((size_t)(b*G + g)*6)*HW + p;
    #pragma unroll
    for (int c = 0; c < 6; ++c) ap[(size_t)c*HW] = acc[c];
}

// ---------------------------------------------------------------------------
// Kernel T: NCHW f32 -> per-group channels-last FP16  xT[(b*G+g)*HW + p][Cg]
// ---------------------------------------------------------------------------
__global__ __launch_bounds__(256) void transpose_kernel(
    const float* __restrict__ x, _Float16* __restrict__ xT)
{
    __shared__ float t[256*33];            // +1 pad: conflict-free both phases
    const int blk  = swizzle_blk(blockIdx.x);
    const int tile = blk % TILES;
    const int g    = (blk / TILES) % G;
    const int b    = blk / (TILES*G);

    const float* xg = x + ((size_t)b*C + g*Cg)*HW + tile*256;
    #pragma unroll
    for (int i = 0; i < Cg; ++i)
        t[threadIdx.x*33 + i] = xg[(size_t)i*HW + threadIdx.x];
    __syncthreads();

    h8* dst = (h8*)(xT + ((size_t)(b*G + g)*HW + (size_t)tile*256)*Cg);
    #pragma unroll
    for (int r = 0; r < 4; ++r) {
        const int idx = r*256 + threadIdx.x;    // chunk: pixel idx>>2, 8ch (idx&3)*8
        const float* s = &t[(idx >> 2)*33 + (idx & 3)*8];
        h8 o;
        #pragma unroll
        for (int j = 0; j < 8; ++j) o[j] = (_Float16)s[j];
        dst[idx] = o;
    }
}

// ---------------------------------------------------------------------------
// Kernel 2: LDS-window fp16 MFMA deformable conv + BN + residual ReLU.
// 16x16 spatial tile per block. Stage 24x24x32ch fp16 window (border-clamped)
// once -> all bilinear corner gathers are ds_read_b128 (each L2 line fetched
// once per block instead of ~16x; fixes the L1-thrash / L2-latency binder of
// rounds 7-8). Rare out-of-window corners (offset outliers) use an exec-
// masked global fallback. Single barrier; no barriers in main loop.
// ---------------------------------------------------------------------------
__global__ __launch_bounds__(256) void deform_mfma_kernel(
    const float* __restrict__ x, const _Float16* __restrict__ xT,
    const float* __restrict__ w_def, const float* __restrict__ aff,
    const float* __restrict__ gamma, const float* __restrict__ beta,
    const float* __restrict__ rmean, const float* __restrict__ rvar,
    float* __restrict__ out)
{
    __shared__ __align__(16) char smem[SMEM_BYTES];
    char* Wsm = smem;            // window
    char* Bsm = smem + W_BYTES;  // weights

    const int blk  = swizzle_blk(blockIdx.x);
    const int tile = blk % TILES;
    const int g    = (blk / TILES) % G;
    const int b    = blk / (TILES*G);
    const int ty   = tile / 6, tx = tile % 6;
    const int h0   = ty*16,    w0 = tx*16;
    const int tid  = threadIdx.x;
    const int lane = tid & 63;
    const int wv   = tid >> 6;
    const int r15  = lane & 15;
    const int koff = lane >> 4;

    const _Float16* xgT_base = xT + (size_t)(b*G + g)*HW*Cg;

    // ---- stage window to LDS: 576 pos x 64B, border-clamped ----
    for (int i = tid; i < WPOS*4; i += 256) {
        const int pos = i >> 2, ch = (i & 3)*8;
        const int wy = pos / WIN, wx = pos % WIN;
        const int y  = min(max(h0 + wy - 4, 0), H-1);
        const int xx = min(max(w0 + wx - 4, 0), W-1);
        *(short8*)(Wsm + pos*W_STRIDE + ch*2) =
            *(const short8*)(xgT_base + ((size_t)y*W + xx)*Cg + ch);
    }
    // ---- stage group weights to LDS (fp16): Bsm[o][K=t*32+i] ----
    for (int l = tid; l < Cg*288; l += 256) {
        const int o = l / 288, K = l % 288;
        const int t = K >> 5, i = K & 31;
        const float wt = w_def[(size_t)(g*Cg + o)*(Cg*9) + i*9 + t];
        *(_Float16*)(Bsm + o*B_STRIDE + K*2) = (_Float16)wt;
    }
    __syncthreads();   // the only barrier

    // ---- per-lane: affine params + coords for its 4 pixels ----
    const float* afb = aff + ((size_t)(b*G + g)*6)*HW;
    float a0[4], a1[4], a2[4], a3[4], a4[4], a5[4];
    float hf[4], wf[4];
    #pragma unroll
    for (int m = 0; m < 4; ++m) {
        const int row = wv*4 + m;
        const int p = (h0 + row)*W + w0 + r15;
        a0[m] = afb[0*(size_t)HW + p];
        a1[m] = afb[1*(size_t)HW + p];
        a2[m] = afb[2*(size_t)HW + p];
        a3[m] = afb[3*(size_t)HW + p];
        a4[m] = afb[4*(size_t)HW + p];
        a5[m] = afb[5*(size_t)HW + p];
        hf[m] = (float)(h0 + row);
        wf[m] = (float)(w0 + r15);
    }

    const _Float16* xgT = xgT_base + koff*8;
    const int kb = koff*16;   // byte offset of this lane's 8-ch slice

    f32x4 acc[4][2];
    #pragma unroll
    for (int m = 0; m < 4; ++m)
        #pragma unroll
        for (int n = 0; n < 2; ++n)
            acc[m][n] = (f32x4){0.f, 0.f, 0.f, 0.f};

    #pragma unroll 1
    for (int t = 0; t < 9; ++t) {
        const float kyf = (float)(t/3 - 1);
        const float kxf = (float)(t%3 - 1);

        h8 af[4];
        #pragma unroll
        for (int m = 0; m < 4; ++m) {
            const float py = hf[m] + kyf + (a0[m]*kyf + a1[m]*kxf + a2[m]);
            const float px = wf[m] + kxf + (a3[m]*kyf + a4[m]*kxf + a5[m]);
            const float y0f = floorf(py), x0f = floorf(px);
            const float fy = py - y0f,   fx = px - x0f;
            const int y0 = (int)y0f, x0 = (int)x0f;
            const int y1 = y0 + 1,   x1 = x0 + 1;
            const bool vy0 = (y0 >= 0) && (y0 < H);
            const bool vy1 = (y1 >= 0) && (y1 < H);
            const bool vx0 = (x0 >= 0) && (x0 < W);
            const bool vx1 = (x1 >= 0) && (x1 < W);
            const float w00f = (vy0 && vx0) ? (1.0f - fy)*(1.0f - fx) : 0.0f;
            const float w01f = (vy0 && vx1) ? (1.0f - fy)*fx          : 0.0f;
            const float w10f = (vy1 && vx0) ? fy*(1.0f - fx)          : 0.0f;
            const float w11f = (vy1 && vx1) ? fy*fx                   : 0.0f;
            const int y0c = min(max(y0, 0), H-1), y1c = min(max(y1, 0), H-1);
            const int x0c = min(max(x0, 0), W-1), x1c = min(max(x1, 0), W-1);

            // window coords (clamped space)
            const int wy0 = y0c - h0 + 4, wy1 = y1c - h0 + 4;
            const int wx0 = x0c - w0 + 4, wx1 = x1c - w0 + 4;
            const bool ok = ((unsigned)wy0 < WIN) & ((unsigned)wy1 < WIN)
                          & ((unsigned)wx0 < WIN) & ((unsigned)wx1 < WIN);

            union { short8 s; h2 h[4]; h8 v; } u00, u01, u10, u11, r;
            if (__builtin_expect(ok, 1)) {
                u00.s = *(const short8*)(Wsm + (wy0*WIN + wx0)*W_STRIDE + kb);
                u01.s = *(const short8*)(Wsm + (wy0*WIN + wx1)*W_STRIDE + kb);
                u10.s = *(const short8*)(Wsm + (wy1*WIN + wx0)*W_STRIDE + kb);
                u11.s = *(const short8*)(Wsm + (wy1*WIN + wx1)*W_STRIDE + kb);
            } else {
                u00.s = *(const short8*)(xgT + (size_t)(y0c*W + x0c)*Cg);
                u01.s = *(const short8*)(xgT + (size_t)(y0c*W + x1c)*Cg);
                u10.s = *(const short8*)(xgT + (size_t)(y1c*W + x0c)*Cg);
                u11.s = *(const short8*)(xgT + (size_t)(y1c*W + x1c)*Cg);
            }

            const _Float16 W00 = (_Float16)w00f, W01 = (_Float16)w01f;
            const _Float16 W10 = (_Float16)w10f, W11 = (_Float16)w11f;
            #pragma unroll
            for (int j = 0; j < 4; ++j)
                r.h[j] = W00*u00.h[j] + W01*u01.h[j] + W10*u10.h[j] + W11*u11.h[j];
            af[m] = r.v;
        }

        #pragma unroll
        for (int n = 0; n < 2; ++n) {
            const h8 bf = *(const h8*)(Bsm + (n*16 + r15)*B_STRIDE + t*64 + kb);
            #pragma unroll
            for (int m = 0; m < 4; ++m)
                acc[m][n] = __builtin_amdgcn_mfma_f32_16x16x32_f16(af[m], bf, acc[m][n], 0, 0, 0);
        }
    }

    // ---- epilogue: BN + residual + ReLU, 16B-chunk stores ----
    #pragma unroll
    for (int m = 0; m < 4; ++m) {
        const int row = wv*4 + m;                       // row in tile
        const int pxg = (h0 + row)*W + w0 + koff*4;     // D row=(lane>>4)*4+reg
        #pragma unroll
        for (int n = 0; n < 2; ++n) {
            const int o = n*16 + r15;
            const int c = g*Cg + o;
            const float inv   = rsqrtf(rvar[c] + BN_EPS);
            const float scale = inv * gamma[c];
            const float shift = beta[c] - rmean[c]*scale;
            const size_t base = ((size_t)b*C + c)*HW + pxg;
            const float4 res = *(const float4*)(x + base);
            float4 ov;
            ov.x = fmaxf(acc[m][n][0]*scale + shift + res.x, 0.0f);
            ov.y = fmaxf(acc[m][n][1]*scale + shift + res.y, 0.0f);
            ov.z = fmaxf(acc[m][n][2]*scale + shift + res.z, 0.0f);
            ov.w = fmaxf(acc[m][n][3]*scale + shift + res.w, 0.0f);
            *(float4*)(out + base) = ov;
        }
    }
}

// ---------------------------------------------------------------------------
// Fallback (NCHW f32 path) if ws is too small for the transposed copy.
// ---------------------------------------------------------------------------
__global__ __launch_bounds__(256) void deform_conv_kernel(
    const float* __restrict__ x, const float* __restrict__ w_def,
    const float* __restrict__ aff, const float* __restrict__ gamma,
    const float* __restrict__ beta, const float* __restrict__ rmean,
    const float* __restrict__ rvar, float* __restrict__ out)
{
    __shared__ float wl[9*Cg*Cg];
    const int blk  = swizzle_blk(blockIdx.x);
    const int tile = blk % TILES;
    const int g    = (blk / TILES) % G;
    const int b    = blk / (TILES*G);

    for (int l = threadIdx.x; l < 9*Cg*Cg; l += 256) {
        int o = l & 31; int i = (l >> 5) & 31; int k = l >> 10;
        wl[l] = w_def[(size_t)(g*Cg + o)*(Cg*9) + i*9 + k];
    }
    __syncthreads();

    const int p = tile*256 + threadIdx.x;
    const int h = p / W, w = p % W;

    const float* ap = aff + ((size_t)(b*G + g)*6)*HW + p;
    const float a0 = ap[0*(size_t)HW], a1 = ap[1*(size_t)HW], a2 = ap[2*(size_t)HW];
    const float a3 = ap[3*(size_t)HW], a4 = ap[4*(size_t)HW], a5 = ap[5*(size_t)HW];

    float acc[Cg];
    #pragma unroll
    for (int o = 0; o < Cg; ++o) acc[o] = 0.0f;

    const float* xg = x + ((size_t)b*C + g*Cg)*HW;

    #pragma unroll
    for (int k = 0; k < 9; ++k) {
        const float kyf = (float)(k/3 - 1);
        const float kxf = (float)(k%3 - 1);
        const float offy = a0*kyf + a1*kxf + a2;
        const float offx = a3*kyf + a4*kxf + a5;
        const float py = (float)h + kyf + offy;
        const float px = (float)w + kxf + offx;
        const float y0f = floorf(py), x0f = floorf(px);
        const float fy = py - y0f,   fx = px - x0f;
        const int y0 = (int)y0f, x0 = (int)x0f;
        const int y1 = y0 + 1,   x1 = x0 + 1;
        const bool vy0 = (y0 >= 0) && (y0 < H);
        const bool vy1 = (y1 >= 0) && (y1 < H);
        const bool vx0 = (x0 >= 0) && (x0 < W);
        const bool vx1 = (x1 >= 0) && (x1 < W);
        const float w00 = (vy0 && vx0) ? (1.0f - fy)*(1.0f - fx) : 0.0f;
        const float w01 = (vy0 && vx1) ? (1.0f - fy)*fx          : 0.0f;
        const float w10 = (vy1 && vx0) ? fy*(1.0f - fx)          : 0.0f;
        const float w11 = (vy1 && vx1) ? fy*fx                   : 0.0f;
        const int y0c = min(max(y0, 0), H-1), y1c = min(max(y1, 0), H-1);
        const int x0c = min(max(x0, 0), W-1), x1c = min(max(x1, 0), W-1);
        const int p00 = y0c*W + x0c, p01 = y0c*W + x1c;
        const int p10 = y1c*W + x0c, p11 = y1c*W + x1c;

        const float* wk = &wl[k*Cg*Cg];
        for (int i = 0; i < Cg; ++i) {
            const float* xc = xg + (size_t)i*HW;
            const float v = w00*xc[p00] + w01*xc[p01] + w10*xc[p10] + w11*xc[p11];
            #pragma unroll
            for (int o = 0; o < Cg; ++o)
                acc[o] = fmaf(v, wk[i*Cg + o], acc[o]);
        }
    }

    float* op = out + ((size_t)b*C + g*Cg)*HW + p;
    #pragma unroll
    for (int o = 0; o < Cg; ++o) {
        const int c = g*Cg + o;
        const float inv = rsqrtf(rvar[c] + BN_EPS);
        float val = (acc[o] - rmean[c]) * (inv * gamma[c]) + beta[c];
        val += xg[(size_t)o*HW + p];
        op[(size_t)o*HW] = fmaxf(val, 0.0f);
    }
}

// ---------------------------------------------------------------------------
extern "C" void kernel_launch(void* const* d_in, const int* in_sizes, int n_in,
                              void* d_out, int out_size, void* d_ws, size_t ws_size,
                              hipStream_t stream) {
    const float* x     = (const float*)d_in[0];
    const float* w_off = (const float*)d_in[1];
    const float* b_off = (const float*)d_in[2];
    const float* w_def = (const float*)d_in[3];
    const float* gamma = (const float*)d_in[4];
    const float* beta  = (const float*)d_in[5];
    const float* rmean = (const float*)d_in[6];
    const float* rvar  = (const float*)d_in[7];
    float* out = (float*)d_out;

    const size_t AFF_BYTES = (size_t)B*G*6*HW*sizeof(float);       // ~15.0 MB
    const size_t XT_BYTES  = (size_t)B*G*HW*Cg*sizeof(_Float16);   // ~40.1 MB
    float* aff = (float*)d_ws;

    offset_conv_kernel<<<NBLK, 256, 0, stream>>>(x, w_off, b_off, aff);

    if (ws_size >= AFF_BYTES + XT_BYTES) {
        _Float16* xT = (_Float16*)((char*)d_ws + AFF_BYTES);
        transpose_kernel<<<NBLK, 256, 0, stream>>>(x, xT);
        deform_mfma_kernel<<<NBLK, 256, 0, stream>>>(x, xT, w_def, aff, gamma,
                                                     beta, rmean, rvar, out);
    } else {
        deform_conv_kernel<<<NBLK, 256, 0, stream>>>(x, w_def, aff, gamma, beta,
                                                     rmean, rvar, out);
    }
}

// Round 10
// 189.083 us; speedup vs baseline: 2.2544x; 1.0033x over previous
//
#include <hip/hip_runtime.h>
#include <math.h>

#define G  17
#define Cg 32
#define B  4
#define C  544
#define H  96
#define W  96
#define HW (H*W)
#define TILES 36         // deform: 6x6 tiles of 16x16 px; offset: 36 strips of 256 px
#define NBLK (B*G*TILES) // 2448 (divisible by 8)
#define BN_EPS 1e-5f

typedef float    f32x4  __attribute__((ext_vector_type(4)));
typedef short    short8 __attribute__((ext_vector_type(8)));
typedef _Float16 h2     __attribute__((ext_vector_type(2)));
typedef _Float16 h8     __attribute__((ext_vector_type(8)));

// ---- deform LDS layout ----
// Window: 20x20 positions (16x16 tile + halo 2), 32ch fp16 per position,
// row stride 80B (16B-aligned; pos*20 dwords %32 -> 8 bank-starts, ~2-way).
// Halo 2 gives in-window margin |off|<1 (sigma~0.3 => ~1.4e-3/corner-set
// fails); out-of-window corners use the exec-masked global fallback.
#define WIN       20
#define HALO      2
#define WPOS      (WIN*WIN)       // 400
#define W_STRIDE  80
#define W_BYTES   (WPOS*W_STRIDE) // 32000
// Weights: 32 o-rows of 288 fp16 (576B) padded to 592B (~2-way).
#define B_STRIDE  592
#define B_BYTES   (Cg*B_STRIDE)   // 18944
#define SMEM_BYTES (W_BYTES + B_BYTES) // 50944 -> 3 blocks/CU (was 65024 -> 2)

// XCD-chunked swizzle (round-4 verified: FETCH 925->87 MB).
__device__ __forceinline__ int swizzle_blk(int blk) {
    return (blk & 7) * (NBLK / 8) + (blk >> 3);
}

// ---------------------------------------------------------------------------
// Kernel 1 (FUSED): grouped 3x3 offset conv -> aff[B][G][6][H][W]
//                   + center-tap extraction -> channels-last fp16 xT.
// The t=4 tap load IS x[p][i]; stash it in LDS and emit the transposed xT
// write from here (round-2 coalesced pattern) -- kills the transpose kernel.
// ---------------------------------------------------------------------------
__global__ __launch_bounds__(256) void offset_conv_fused_kernel(
    const float* __restrict__ x, const float* __restrict__ w_off,
    const float* __restrict__ b_off, float* __restrict__ aff,
    _Float16* __restrict__ xT)
{
    __shared__ float wl[Cg*9*6];           // layout [i][t][c]
    __shared__ float ts[256*33];           // +1 pad: conflict-free both phases
    const int blk  = swizzle_blk(blockIdx.x);
    const int tile = blk % TILES;
    const int g    = (blk / TILES) % G;
    const int b    = blk / (TILES*G);

    for (int l = threadIdx.x; l < Cg*9*6; l += 256) {
        int c = l % 6; int t = (l/6) % 9; int i = l/54;
        wl[l] = w_off[(size_t)(g*6 + c)*(Cg*9) + i*9 + t];
    }
    __syncthreads();

    const int p = tile*256 + threadIdx.x;
    const int h = p / W, w = p % W;

    float acc[6];
    #pragma unroll
    for (int c = 0; c < 6; ++c) acc[c] = b_off[g*6 + c];

    const float* xg = x + ((size_t)b*C + g*Cg)*HW;
    for (int i = 0; i < Cg; ++i) {
        const float* xc = xg + (size_t)i*HW;
        #pragma unroll
        for (int t = 0; t < 9; ++t) {
            const int dy = t/3 - 1, dx = t%3 - 1;
            const int yy = h + dy, xx = w + dx;
            float v = (yy >= 0 && yy < H && xx >= 0 && xx < W) ? xc[yy*W + xx] : 0.0f;
            if (t == 4) ts[threadIdx.x*33 + i] = v;   // center tap -> xT staging
            #pragma unroll
            for (int c = 0; c < 6; ++c)
                acc[c] = fmaf(v, wl[(i*9 + t)*6 + c], acc[c]);
        }
    }

    float* ap = aff + ((size_t)(b*G + g)*6)*HW + p;
    #pragma unroll
    for (int c = 0; c < 6; ++c) ap[(size_t)c*HW] = acc[c];

    __syncthreads();
    // coalesced fp16 xT write: consecutive threads -> consecutive 16B chunks
    h8* dst = (h8*)(xT + ((size_t)(b*G + g)*HW + (size_t)tile*256)*Cg);
    #pragma unroll
    for (int r = 0; r < 4; ++r) {
        const int idx = r*256 + threadIdx.x;    // pixel idx>>2, 8ch (idx&3)*8
        const float* s = &ts[(idx >> 2)*33 + (idx & 3)*8];
        h8 o;
        #pragma unroll
        for (int j = 0; j < 8; ++j) o[j] = (_Float16)s[j];
        dst[idx] = o;
    }
}

// ---------------------------------------------------------------------------
// Kernel 2: LDS-window fp16 MFMA deformable conv + BN + residual ReLU.
// 16x16 spatial tile per block; 20x20x32ch window staged once (border-
// clamped); all bilinear corner gathers are ds_read_b128. Out-of-window
// corners -> exec-masked global fallback. Single barrier.
// ---------------------------------------------------------------------------
__global__ __launch_bounds__(256) void deform_mfma_kernel(
    const float* __restrict__ x, const _Float16* __restrict__ xT,
    const float* __restrict__ w_def, const float* __restrict__ aff,
    const float* __restrict__ gamma, const float* __restrict__ beta,
    const float* __restrict__ rmean, const float* __restrict__ rvar,
    float* __restrict__ out)
{
    __shared__ __align__(16) char smem[SMEM_BYTES];
    char* Wsm = smem;            // window
    char* Bsm = smem + W_BYTES;  // weights

    const int blk  = swizzle_blk(blockIdx.x);
    const int tile = blk % TILES;
    const int g    = (blk / TILES) % G;
    const int b    = blk / (TILES*G);
    const int ty   = tile / 6, tx = tile % 6;
    const int h0   = ty*16,    w0 = tx*16;
    const int tid  = threadIdx.x;
    const int lane = tid & 63;
    const int wv   = tid >> 6;
    const int r15  = lane & 15;
    const int koff = lane >> 4;

    const _Float16* xgT_base = xT + (size_t)(b*G + g)*HW*Cg;

    // ---- stage window to LDS: 400 pos x 64B, border-clamped ----
    for (int i = tid; i < WPOS*4; i += 256) {
        const int pos = i >> 2, ch = (i & 3)*8;
        const int wy = pos / WIN, wx = pos % WIN;
        const int y  = min(max(h0 + wy - HALO, 0), H-1);
        const int xx = min(max(w0 + wx - HALO, 0), W-1);
        *(short8*)(Wsm + pos*W_STRIDE + ch*2) =
            *(const short8*)(xgT_base + ((size_t)y*W + xx)*Cg + ch);
    }
    // ---- stage group weights to LDS (fp16): Bsm[o][K=t*32+i] ----
    for (int l = tid; l < Cg*288; l += 256) {
        const int o = l / 288, K = l % 288;
        const int t = K >> 5, i = K & 31;
        const float wt = w_def[(size_t)(g*Cg + o)*(Cg*9) + i*9 + t];
        *(_Float16*)(Bsm + o*B_STRIDE + K*2) = (_Float16)wt;
    }
    __syncthreads();   // the only barrier

    // ---- per-lane: affine params + coords for its 4 pixels ----
    const float* afb = aff + ((size_t)(b*G + g)*6)*HW;
    float a0[4], a1[4], a2[4], a3[4], a4[4], a5[4];
    float hf[4], wf[4];
    #pragma unroll
    for (int m = 0; m < 4; ++m) {
        const int row = wv*4 + m;
        const int p = (h0 + row)*W + w0 + r15;
        a0[m] = afb[0*(size_t)HW + p];
        a1[m] = afb[1*(size_t)HW + p];
        a2[m] = afb[2*(size_t)HW + p];
        a3[m] = afb[3*(size_t)HW + p];
        a4[m] = afb[4*(size_t)HW + p];
        a5[m] = afb[5*(size_t)HW + p];
        hf[m] = (float)(h0 + row);
        wf[m] = (float)(w0 + r15);
    }

    const _Float16* xgT = xgT_base + koff*8;
    const int kb = koff*16;   // byte offset of this lane's 8-ch slice

    f32x4 acc[4][2];
    #pragma unroll
    for (int m = 0; m < 4; ++m)
        #pragma unroll
        for (int n = 0; n < 2; ++n)
            acc[m][n] = (f32x4){0.f, 0.f, 0.f, 0.f};

    #pragma unroll 1
    for (int t = 0; t < 9; ++t) {
        const float kyf = (float)(t/3 - 1);
        const float kxf = (float)(t%3 - 1);

        h8 af[4];
        #pragma unroll
        for (int m = 0; m < 4; ++m) {
            const float py = hf[m] + kyf + (a0[m]*kyf + a1[m]*kxf + a2[m]);
            const float px = wf[m] + kxf + (a3[m]*kyf + a4[m]*kxf + a5[m]);
            const float y0f = floorf(py), x0f = floorf(px);
            const float fy = py - y0f,   fx = px - x0f;
            const int y0 = (int)y0f, x0 = (int)x0f;
            const int y1 = y0 + 1,   x1 = x0 + 1;
            const bool vy0 = (y0 >= 0) && (y0 < H);
            const bool vy1 = (y1 >= 0) && (y1 < H);
            const bool vx0 = (x0 >= 0) && (x0 < W);
            const bool vx1 = (x1 >= 0) && (x1 < W);
            const float w00f = (vy0 && vx0) ? (1.0f - fy)*(1.0f - fx) : 0.0f;
            const float w01f = (vy0 && vx1) ? (1.0f - fy)*fx          : 0.0f;
            const float w10f = (vy1 && vx0) ? fy*(1.0f - fx)          : 0.0f;
            const float w11f = (vy1 && vx1) ? fy*fx                   : 0.0f;
            const int y0c = min(max(y0, 0), H-1), y1c = min(max(y1, 0), H-1);
            const int x0c = min(max(x0, 0), W-1), x1c = min(max(x1, 0), W-1);

            // window coords (clamped space)
            const int wy0 = y0c - h0 + HALO, wy1 = y1c - h0 + HALO;
            const int wx0 = x0c - w0 + HALO, wx1 = x1c - w0 + HALO;
            const bool ok = ((unsigned)wy0 < WIN) & ((unsigned)wy1 < WIN)
                          & ((unsigned)wx0 < WIN) & ((unsigned)wx1 < WIN);

            union { short8 s; h2 h[4]; h8 v; } u00, u01, u10, u11, r;
            if (__builtin_expect(ok, 1)) {
                u00.s = *(const short8*)(Wsm + (wy0*WIN + wx0)*W_STRIDE + kb);
                u01.s = *(const short8*)(Wsm + (wy0*WIN + wx1)*W_STRIDE + kb);
                u10.s = *(const short8*)(Wsm + (wy1*WIN + wx0)*W_STRIDE + kb);
                u11.s = *(const short8*)(Wsm + (wy1*WIN + wx1)*W_STRIDE + kb);
            } else {
                u00.s = *(const short8*)(xgT + (size_t)(y0c*W + x0c)*Cg);
                u01.s = *(const short8*)(xgT + (size_t)(y0c*W + x1c)*Cg);
                u10.s = *(const short8*)(xgT + (size_t)(y1c*W + x0c)*Cg);
                u11.s = *(const short8*)(xgT + (size_t)(y1c*W + x1c)*Cg);
            }

            const _Float16 W00 = (_Float16)w00f, W01 = (_Float16)w01f;
            const _Float16 W10 = (_Float16)w10f, W11 = (_Float16)w11f;
            #pragma unroll
            for (int j = 0; j < 4; ++j)
                r.h[j] = W00*u00.h[j] + W01*u01.h[j] + W10*u10.h[j] + W11*u11.h[j];
            af[m] = r.v;
        }

        #pragma unroll
        for (int n = 0; n < 2; ++n) {
            const h8 bf = *(const h8*)(Bsm + (n*16 + r15)*B_STRIDE + t*64 + kb);
            #pragma unroll
            for (int m = 0; m < 4; ++m)
                acc[m][n] = __builtin_amdgcn_mfma_f32_16x16x32_f16(af[m], bf, acc[m][n], 0, 0, 0);
        }
    }

    // ---- epilogue: BN + residual + ReLU, 16B-chunk stores ----
    #pragma unroll
    for (int m = 0; m < 4; ++m) {
        const int row = wv*4 + m;
        const int pxg = (h0 + row)*W + w0 + koff*4;     // D row=(lane>>4)*4+reg
        #pragma unroll
        for (int n = 0; n < 2; ++n) {
            const int o = n*16 + r15;
            const int c = g*Cg + o;
            const float inv   = rsqrtf(rvar[c] + BN_EPS);
            const float scale = inv * gamma[c];
            const float shift = beta[c] - rmean[c]*scale;
            const size_t base = ((size_t)b*C + c)*HW + pxg;
            const float4 res = *(const float4*)(x + base);
            float4 ov;
            ov.x = fmaxf(acc[m][n][0]*scale + shift + res.x, 0.0f);
            ov.y = fmaxf(acc[m][n][1]*scale + shift + res.y, 0.0f);
            ov.z = fmaxf(acc[m][n][2]*scale + shift + res.z, 0.0f);
            ov.w = fmaxf(acc[m][n][3]*scale + shift + res.w, 0.0f);
            *(float4*)(out + base) = ov;
        }
    }
}

// ---------------------------------------------------------------------------
// Fallback pair (NCHW f32 path) if ws is too small for aff + xT.
// ---------------------------------------------------------------------------
__global__ __launch_bounds__(256) void offset_conv_kernel(
    const float* __restrict__ x, const float* __restrict__ w_off,
    const float* __restrict__ b_off, float* __restrict__ aff)
{
    __shared__ float wl[Cg*9*6];
    const int blk  = swizzle_blk(blockIdx.x);
    const int tile = blk % TILES;
    const int g    = (blk / TILES) % G;
    const int b    = blk / (TILES*G);

    for (int l = threadIdx.x; l < Cg*9*6; l += 256) {
        int c = l % 6; int t = (l/6) % 9; int i = l/54;
        wl[l] = w_off[(size_t)(g*6 + c)*(Cg*9) + i*9 + t];
    }
    __syncthreads();

    const int p = tile*256 + threadIdx.x;
    const int h = p / W, w = p % W;

    float acc[6];
    #pragma unroll
    for (int c = 0; c < 6; ++c) acc[c] = b_off[g*6 + c];

    const float* xg = x + ((size_t)b*C + g*Cg)*HW;
    for (int i = 0; i < Cg; ++i) {
        const float* xc = xg + (size_t)i*HW;
        #pragma unroll
        for (int t = 0; t < 9; ++t) {
            const int dy = t/3 - 1, dx = t%3 - 1;
            const int yy = h + dy, xx = w + dx;
            float v = (yy >= 0 && yy < H && xx >= 0 && xx < W) ? xc[yy*W + xx] : 0.0f;
            #pragma unroll
            for (int c = 0; c < 6; ++c)
                acc[c] = fmaf(v, wl[(i*9 + t)*6 + c], acc[c]);
        }
    }

    float* ap = aff + ((size_t)(b*G + g)*6)*HW + p;
    #pragma unroll
    for (int c = 0; c < 6; ++c) ap[(size_t)c*HW] = acc[c];
}

__global__ __launch_bounds__(256) void deform_conv_kernel(
    const float* __restrict__ x, const float* __restrict__ w_def,
    const float* __restrict__ aff, const float* __restrict__ gamma,
    const float* __restrict__ beta, const float* __restrict__ rmean,
    const float* __restrict__ rvar, float* __restrict__ out)
{
    __shared__ float wl[9*Cg*Cg];
    const int blk  = swizzle_blk(blockIdx.x);
    const int tile = blk % TILES;
    const int g    = (blk / TILES) % G;
    const int b    = blk / (TILES*G);

    for (int l = threadIdx.x; l < 9*Cg*Cg; l += 256) {
        int o = l & 31; int i = (l >> 5) & 31; int k = l >> 10;
        wl[l] = w_def[(size_t)(g*Cg + o)*(Cg*9) + i*9 + k];
    }
    __syncthreads();

    const int p = tile*256 + threadIdx.x;
    const int h = p / W, w = p % W;

    const float* ap = aff + ((size_t)(b*G + g)*6)*HW + p;
    const float a0 = ap[0*(size_t)HW], a1 = ap[1*(size_t)HW], a2 = ap[2*(size_t)HW];
    const float a3 = ap[3*(size_t)HW], a4 = ap[4*(size_t)HW], a5 = ap[5*(size_t)HW];

    float acc[Cg];
    #pragma unroll
    for (int o = 0; o < Cg; ++o) acc[o] = 0.0f;

    const float* xg = x + ((size_t)b*C + g*Cg)*HW;

    #pragma unroll
    for (int k = 0; k < 9; ++k) {
        const float kyf = (float)(k/3 - 1);
        const float kxf = (float)(k%3 - 1);
        const float offy = a0*kyf + a1*kxf + a2;
        const float offx = a3*kyf + a4*kxf + a5;
        const float py = (float)h + kyf + offy;
        const float px = (float)w + kxf + offx;
        const float y0f = floorf(py), x0f = floorf(px);
        const float fy = py - y0f,   fx = px - x0f;
        const int y0 = (int)y0f, x0 = (int)x0f;
        const int y1 = y0 + 1,   x1 = x0 + 1;
        const bool vy0 = (y0 >= 0) && (y0 < H);
        const bool vy1 = (y1 >= 0) && (y1 < H);
        const bool vx0 = (x0 >= 0) && (x0 < W);
        const bool vx1 = (x1 >= 0) && (x1 < W);
        const float w00 = (vy0 && vx0) ? (1.0f - fy)*(1.0f - fx) : 0.0f;
        const float w01 = (vy0 && vx1) ? (1.0f - fy)*fx          : 0.0f;
        const float w10 = (vy1 && vx0) ? fy*(1.0f - fx)          : 0.0f;
        const float w11 = (vy1 && vx1) ? fy*fx                   : 0.0f;
        const int y0c = min(max(y0, 0), H-1), y1c = min(max(y1, 0), H-1);
        const int x0c = min(max(x0, 0), W-1), x1c = min(max(x1, 0), W-1);
        const int p00 = y0c*W + x0c, p01 = y0c*W + x1c;
        const int p10 = y1c*W + x0c, p11 = y1c*W + x1c;

        const float* wk = &wl[k*Cg*Cg];
        for (int i = 0; i < Cg; ++i) {
            const float* xc = xg + (size_t)i*HW;
            const float v = w00*xc[p00] + w01*xc[p01] + w10*xc[p10] + w11*xc[p11];
            #pragma unroll
            for (int o = 0; o < Cg; ++o)
                acc[o] = fmaf(v, wk[i*Cg + o], acc[o]);
        }
    }

    float* op = out + ((size_t)b*C + g*Cg)*HW + p;
    #pragma unroll
    for (int o = 0; o < Cg; ++o) {
        const int c = g*Cg + o;
        const float inv = rsqrtf(rvar[c] + BN_EPS);
        float val = (acc[o] - rmean[c]) * (inv * gamma[c]) + beta[c];
        val += xg[(size_t)o*HW + p];
        op[(size_t)o*HW] = fmaxf(val, 0.0f);
    }
}

// ---------------------------------------------------------------------------
extern "C" void kernel_launch(void* const* d_in, const int* in_sizes, int n_in,
                              void* d_out, int out_size, void* d_ws, size_t ws_size,
                              hipStream_t stream) {
    const float* x     = (const float*)d_in[0];
    const float* w_off = (const float*)d_in[1];
    const float* b_off = (const float*)d_in[2];
    const float* w_def = (const float*)d_in[3];
    const float* gamma = (const float*)d_in[4];
    const float* beta  = (const float*)d_in[5];
    const float* rmean = (const float*)d_in[6];
    const float* rvar  = (const float*)d_in[7];
    float* out = (float*)d_out;

    const size_t AFF_BYTES = (size_t)B*G*6*HW*sizeof(float);       // ~15.0 MB
    const size_t XT_BYTES  = (size_t)B*G*HW*Cg*sizeof(_Float16);   // ~40.1 MB
    float* aff = (float*)d_ws;

    if (ws_size >= AFF_BYTES + XT_BYTES) {
        _Float16* xT = (_Float16*)((char*)d_ws + AFF_BYTES);
        offset_conv_fused_kernel<<<NBLK, 256, 0, stream>>>(x, w_off, b_off, aff, xT);
        deform_mfma_kernel<<<NBLK, 256, 0, stream>>>(x, xT, w_def, aff, gamma,
                                                     beta, rmean, rvar, out);
    } else {
        offset_conv_kernel<<<NBLK, 256, 0, stream>>>(x, w_off, b_off, aff);
        deform_conv_kernel<<<NBLK, 256, 0, stream>>>(x, w_def, aff, gamma, beta,
                                                     rmean, rvar, out);
    }
}